// Round 1
// baseline (8756.510 us; speedup 1.0000x reference)
//
#include <hip/hip_runtime.h>
#include <cstddef>

// ---------------------------------------------------------------------------
// VQ-VAE forward, fp32 direct convolutions.
// Shapes: x (32,3,256,256)
//  enc0: 3->64  s2 -> (32,64,128,128)
//  enc1: 64->128 s2 -> (32,128,64,64)
//  enc2: 128->64 s1 -> (32,64,64,64)
//  quantize vs codebook (512,64)
//  dec0: 64->128 convT s1 -> (32,128,64,64)
//  dec1: 128->64 convT s2 -> (32,64,128,128)
//  dec2: 64->3  convT s2 -> (32,3,256,256)
// ---------------------------------------------------------------------------

// 3x3 conv, stride S, pad 1. Block = 256 threads = TR x TC spatial tile,
// COC output channels accumulated in registers. Input tile staged in LDS per ci.
// ADDSELF: out = (relu?)(acc + addend[idx]) with addend == out (in-place skip add).
// DECONVW: weights are (CIN, COUT, 3, 3) and spatially flipped (ConvTranspose s1).
template<int CIN, int COC, int S, int TR, int TC, bool RELU, bool ADDSELF, bool DECONVW>
__launch_bounds__(256)
__global__ void conv3x3_k(const float* __restrict__ in, const float* __restrict__ w,
                          const float* __restrict__ bias, float* out,
                          const float* addend,
                          int N, int COUT, int Hin, int Win, int Hout, int Wout)
{
    constexpr int HR = (TR - 1) * S + 3;
    constexpr int WR = (TC - 1) * S + 3;
    __shared__ float sm[HR * WR];

    const int tid = threadIdx.x;
    int b = blockIdx.x;
    const int chunks = COUT / COC;
    const int tilesX = Wout / TC;
    const int tilesY = Hout / TR;
    const int ch = b % chunks; b /= chunks;
    const int tx = b % tilesX; b /= tilesX;
    const int ty = b % tilesY; const int n = b / tilesY;

    const int tty = tid / TC, ttx = tid % TC;
    const int oy = ty * TR + tty, ox = tx * TC + ttx;
    const int gy0 = ty * TR * S - 1, gx0 = tx * TC * S - 1;
    const int cobase = ch * COC;

    float acc[COC];
#pragma unroll
    for (int c = 0; c < COC; ++c) acc[c] = bias[cobase + c];

    const size_t inPlane = (size_t)Hin * Win;
    const float* ip0 = in + (size_t)n * CIN * inPlane;

    for (int ci = 0; ci < CIN; ++ci) {
        __syncthreads();
        const float* ip = ip0 + (size_t)ci * inPlane;
        for (int i = tid; i < HR * WR; i += 256) {
            int r = i / WR;
            int c2 = i - r * WR;
            int gy = gy0 + r, gx = gx0 + c2;
            float v = 0.f;
            if (gy >= 0 && gy < Hin && gx >= 0 && gx < Win) v = ip[(size_t)gy * Win + gx];
            sm[i] = v;
        }
        __syncthreads();
        const int r0 = tty * S, c0 = ttx * S;
        float t00 = sm[(r0 + 0) * WR + c0 + 0], t01 = sm[(r0 + 0) * WR + c0 + 1], t02 = sm[(r0 + 0) * WR + c0 + 2];
        float t10 = sm[(r0 + 1) * WR + c0 + 0], t11 = sm[(r0 + 1) * WR + c0 + 1], t12 = sm[(r0 + 1) * WR + c0 + 2];
        float t20 = sm[(r0 + 2) * WR + c0 + 0], t21 = sm[(r0 + 2) * WR + c0 + 1], t22 = sm[(r0 + 2) * WR + c0 + 2];
#pragma unroll
        for (int c = 0; c < COC; ++c) {
            const float* wp = DECONVW ? (w + ((size_t)ci * COUT + (cobase + c)) * 9)
                                      : (w + ((size_t)(cobase + c) * CIN + ci) * 9);
            float w0, w1, w2, w3, w4, w5, w6, w7, w8;
            if (DECONVW) { w0 = wp[8]; w1 = wp[7]; w2 = wp[6]; w3 = wp[5]; w4 = wp[4]; w5 = wp[3]; w6 = wp[2]; w7 = wp[1]; w8 = wp[0]; }
            else         { w0 = wp[0]; w1 = wp[1]; w2 = wp[2]; w3 = wp[3]; w4 = wp[4]; w5 = wp[5]; w6 = wp[6]; w7 = wp[7]; w8 = wp[8]; }
            float a = acc[c];
            a = fmaf(t00, w0, a); a = fmaf(t01, w1, a); a = fmaf(t02, w2, a);
            a = fmaf(t10, w3, a); a = fmaf(t11, w4, a); a = fmaf(t12, w5, a);
            a = fmaf(t20, w6, a); a = fmaf(t21, w7, a); a = fmaf(t22, w8, a);
            acc[c] = a;
        }
    }

    const size_t outPlane = (size_t)Hout * Wout;
    float* op = out + ((size_t)n * COUT + cobase) * outPlane + (size_t)oy * Wout + ox;
    const float* ap = ADDSELF ? (addend + ((size_t)n * COUT + cobase) * outPlane + (size_t)oy * Wout + ox) : nullptr;
#pragma unroll
    for (int c = 0; c < COC; ++c) {
        float v = acc[c];
        if (ADDSELF) v += ap[(size_t)c * outPlane];
        if (RELU) v = fmaxf(v, 0.f);
        op[(size_t)c * outPlane] = v;
    }
}

// 1x1 conv, stride S (ResNet downsample skip). No LDS; tap kept in register
// and reused across COC output channels.
template<int CIN, int COC, int S, bool RELU>
__launch_bounds__(256)
__global__ void conv1x1_k(const float* __restrict__ in, const float* __restrict__ w,
                          const float* __restrict__ bias, float* __restrict__ out,
                          int N, int COUT, int Hin, int Win, int Hout, int Wout)
{
    const int tid = threadIdx.x;
    int b = blockIdx.x;
    const int chunks = COUT / COC;
    const int spB = (Hout * Wout) / 256;
    const int sb = b % spB; b /= spB;
    const int ch = b % chunks; const int n = b / chunks;
    const int pos = sb * 256 + tid;
    const int oy = pos / Wout, ox = pos - oy * Wout;
    const int cobase = ch * COC;

    float acc[COC];
#pragma unroll
    for (int c = 0; c < COC; ++c) acc[c] = bias[cobase + c];

    const size_t inPlane = (size_t)Hin * Win;
    const float* ip = in + (size_t)n * CIN * inPlane + (size_t)(oy * S) * Win + (size_t)(ox * S);
    for (int ci = 0; ci < CIN; ++ci) {
        float v = ip[(size_t)ci * inPlane];
#pragma unroll
        for (int c = 0; c < COC; ++c)
            acc[c] = fmaf(v, w[(size_t)(cobase + c) * CIN + ci], acc[c]);
    }
    const size_t outPlane = (size_t)Hout * Wout;
    float* op = out + ((size_t)n * COUT + cobase) * outPlane + pos;
#pragma unroll
    for (int c = 0; c < COC; ++c) {
        float v = acc[c];
        if (RELU) v = fmaxf(v, 0.f);
        op[(size_t)c * outPlane] = v;
    }
}

// ConvTranspose2d k=3, stride=2, pad=1, output_padding=1 (Hout = 2*Hin).
// Each thread computes a 2x2 output quad from a 2x2 input patch; each of the
// 9 weights is used exactly once per (quad, ci, co) -> no divergence, no waste.
// w layout: (CIN, COUT, 3, 3) (PyTorch ConvTranspose layout, NOT flipped:
// out(2i-1+ky, 2j-1+kx) += in(i,j) * w[ci][co][ky][kx]).
template<int CIN, int COC, int TRQ, int TCQ, bool RELU>
__launch_bounds__(256)
__global__ void deconv2_k(const float* __restrict__ in, const float* __restrict__ w,
                          const float* __restrict__ bias, float* __restrict__ out,
                          int N, int COUT, int Hin, int Win, int Hout, int Wout)
{
    constexpr int HR = TRQ + 1, WR = TCQ + 1;
    __shared__ float sm[HR * WR];

    const int tid = threadIdx.x;
    int b = blockIdx.x;
    const int chunks = COUT / COC;
    const int qTX = (Wout / 2) / TCQ;
    const int qTY = (Hout / 2) / TRQ;
    const int ch = b % chunks; b /= chunks;
    const int qtx = b % qTX; b /= qTX;
    const int qty = b % qTY; const int n = b / qTY;

    const int tqy = tid / TCQ, tqx = tid % TCQ;
    const int qy = qty * TRQ + tqy, qx = qtx * TCQ + tqx;
    const int gy0 = qty * TRQ, gx0 = qtx * TCQ;
    const int cobase = ch * COC;

    float a00[COC], a01[COC], a10[COC], a11[COC];
#pragma unroll
    for (int c = 0; c < COC; ++c) {
        float bb = bias[cobase + c];
        a00[c] = bb; a01[c] = bb; a10[c] = bb; a11[c] = bb;
    }

    const size_t inPlane = (size_t)Hin * Win;
    const float* ip0 = in + (size_t)n * CIN * inPlane;

    for (int ci = 0; ci < CIN; ++ci) {
        __syncthreads();
        const float* ip = ip0 + (size_t)ci * inPlane;
        for (int i = tid; i < HR * WR; i += 256) {
            int r = i / WR, c2 = i - r * WR;
            int gy = gy0 + r, gx = gx0 + c2;
            float v = 0.f;
            if (gy < Hin && gx < Win) v = ip[(size_t)gy * Win + gx];
            sm[i] = v;
        }
        __syncthreads();
        float A = sm[tqy * WR + tqx],       B = sm[tqy * WR + tqx + 1];
        float C = sm[(tqy + 1) * WR + tqx], D = sm[(tqy + 1) * WR + tqx + 1];
#pragma unroll
        for (int c = 0; c < COC; ++c) {
            const float* wp = w + ((size_t)ci * COUT + cobase + c) * 9;
            float w00 = wp[0], w01 = wp[1], w02 = wp[2];
            float w10 = wp[3], w11 = wp[4], w12 = wp[5];
            float w20 = wp[6], w21 = wp[7], w22 = wp[8];
            a00[c] = fmaf(A, w11, a00[c]);
            a01[c] = fmaf(A, w12, a01[c]); a01[c] = fmaf(B, w10, a01[c]);
            a10[c] = fmaf(A, w21, a10[c]); a10[c] = fmaf(C, w01, a10[c]);
            a11[c] = fmaf(A, w22, a11[c]); a11[c] = fmaf(B, w20, a11[c]);
            a11[c] = fmaf(C, w02, a11[c]); a11[c] = fmaf(D, w00, a11[c]);
        }
    }

    const size_t outPlane = (size_t)Hout * Wout;
    const int oy = 2 * qy, ox = 2 * qx;
    float* op = out + ((size_t)n * COUT + cobase) * outPlane + (size_t)oy * Wout + ox;
#pragma unroll
    for (int c = 0; c < COC; ++c) {
        float v00 = a00[c], v01 = a01[c], v10 = a10[c], v11 = a11[c];
        if (RELU) { v00 = fmaxf(v00, 0.f); v01 = fmaxf(v01, 0.f); v10 = fmaxf(v10, 0.f); v11 = fmaxf(v11, 0.f); }
        float2* r0p = reinterpret_cast<float2*>(op + (size_t)c * outPlane);
        float2* r1p = reinterpret_cast<float2*>(op + (size_t)c * outPlane + Wout);
        *r0p = make_float2(v00, v01);
        *r1p = make_float2(v10, v11);
    }
}

// Nearest-codebook quantize. h,q: (32,64,64,64); cb: (512,64).
// One thread per spatial position; e-vector in registers, codebook streamed
// through LDS in 128-code chunks. d = ||c||^2 - 2 e.c (||e||^2 is a monotone
// shift, argmin-invariant). Strict '<' keeps the first index (np.argmin tie rule).
__launch_bounds__(256)
__global__ void quantize_k(const float* __restrict__ h, const float* __restrict__ cb,
                           float* __restrict__ q)
{
    __shared__ float cn[512];
    __shared__ float cbl[128 * 64];
    const int tid = threadIdx.x;

    for (int i = tid; i < 512; i += 256) {
        float s = 0.f;
#pragma unroll
        for (int j = 0; j < 64; ++j) { float v = cb[i * 64 + j]; s = fmaf(v, v, s); }
        cn[i] = s;
    }

    const int t = blockIdx.x * 256 + tid;
    const int n = t >> 12, rem = t & 4095;
    const float* hp = h + (size_t)n * 64 * 4096 + rem;
    float e[64];
#pragma unroll
    for (int j = 0; j < 64; ++j) e[j] = hp[(size_t)j * 4096];

    float best = 3.4e38f; int bi = 0;
    for (int chn = 0; chn < 4; ++chn) {
        __syncthreads();
        const float4* src = reinterpret_cast<const float4*>(cb + chn * 128 * 64);
        float4* dst = reinterpret_cast<float4*>(cbl);
        for (int i = tid; i < 128 * 64 / 4; i += 256) dst[i] = src[i];
        __syncthreads();
        for (int c = 0; c < 128; ++c) {
            float dot = 0.f;
#pragma unroll
            for (int j = 0; j < 64; ++j) dot = fmaf(e[j], cbl[c * 64 + j], dot);
            float d = cn[chn * 128 + c] - 2.f * dot;
            if (d < best) { best = d; bi = chn * 128 + c; }
        }
    }

    const float* crow = cb + (size_t)bi * 64;
    float* qp = q + (size_t)n * 64 * 4096 + rem;
#pragma unroll
    for (int j = 0; j < 64; ++j) qp[(size_t)j * 4096] = crow[j];
}

extern "C" void kernel_launch(void* const* d_in, const int* in_sizes, int n_in,
                              void* d_out, int out_size, void* d_ws, size_t ws_size,
                              hipStream_t stream)
{
    const float* x    = (const float*)d_in[0];
    const float* e0w1 = (const float*)d_in[1];  const float* e0b1 = (const float*)d_in[2];
    const float* e0w2 = (const float*)d_in[3];  const float* e0b2 = (const float*)d_in[4];
    const float* e0wd = (const float*)d_in[5];  const float* e0bd = (const float*)d_in[6];
    const float* e1w1 = (const float*)d_in[7];  const float* e1b1 = (const float*)d_in[8];
    const float* e1w2 = (const float*)d_in[9];  const float* e1b2 = (const float*)d_in[10];
    const float* e1wd = (const float*)d_in[11]; const float* e1bd = (const float*)d_in[12];
    const float* e2w1 = (const float*)d_in[13]; const float* e2b1 = (const float*)d_in[14];
    const float* e2w2 = (const float*)d_in[15]; const float* e2b2 = (const float*)d_in[16];
    const float* e2wd = (const float*)d_in[17]; const float* e2bd = (const float*)d_in[18];
    const float* d0w  = (const float*)d_in[19]; const float* d0b  = (const float*)d_in[20];
    const float* d1w  = (const float*)d_in[21]; const float* d1b  = (const float*)d_in[22];
    const float* d2w  = (const float*)d_in[23]; const float* d2b  = (const float*)d_in[24];
    const float* cb   = (const float*)d_in[25];
    float* out = (float*)d_out;

    // Workspace: two 128 MiB regions (256 MiB total), buffers reused by liveness.
    float* R0 = (float*)d_ws;            // 33,554,432 floats
    float* R1 = R0 + 33554432;           // 33,554,432 floats

    float* S0 = R1;                 // enc0 skip, then h0 (32,64,128,128)
    float* T1 = R0;                 // enc0 conv1 out
    float* S1 = R0;                 // enc1 skip, then h1 (32,128,64,64)
    float* T3 = R0 + 16777216;      // enc1 conv1 out
    float* S2 = R1;                 // enc2 skip, then h2 (32,64,64,64)
    float* T5 = R1 + 8388608;       // enc2 conv1 out
    float* Q  = R0;                 // quantized (32,64,64,64)
    float* D0 = R0 + 16777216;      // dec0 out (32,128,64,64)
    float* D1 = R1;                 // dec1 out (32,64,128,128)

    dim3 blk(256);

    // --- enc0 (3 -> 64, stride 2): 256x256 -> 128x128 ---
    conv1x1_k<3, 64, 2, false><<<dim3(32 * 1 * 64), blk, 0, stream>>>(
        x, e0wd, e0bd, S0, 32, 64, 256, 256, 128, 128);
    conv3x3_k<3, 64, 2, 4, 64, true, false, false><<<dim3(32 * 32 * 2 * 1), blk, 0, stream>>>(
        x, e0w1, e0b1, T1, nullptr, 32, 64, 256, 256, 128, 128);
    conv3x3_k<64, 64, 1, 8, 32, true, true, false><<<dim3(32 * 16 * 4 * 1), blk, 0, stream>>>(
        T1, e0w2, e0b2, S0, S0, 32, 64, 128, 128, 128, 128);

    // --- enc1 (64 -> 128, stride 2): 128x128 -> 64x64 ---
    conv1x1_k<64, 64, 2, false><<<dim3(32 * 2 * 16), blk, 0, stream>>>(
        S0, e1wd, e1bd, S1, 32, 128, 128, 128, 64, 64);
    conv3x3_k<64, 64, 2, 4, 64, true, false, false><<<dim3(32 * 16 * 1 * 2), blk, 0, stream>>>(
        S0, e1w1, e1b1, T3, nullptr, 32, 128, 128, 128, 64, 64);
    conv3x3_k<128, 64, 1, 8, 32, true, true, false><<<dim3(32 * 8 * 2 * 2), blk, 0, stream>>>(
        T3, e1w2, e1b2, S1, S1, 32, 128, 64, 64, 64, 64);

    // --- enc2 (128 -> 64, stride 1): 64x64 -> 64x64 ---
    conv1x1_k<128, 64, 1, false><<<dim3(32 * 1 * 16), blk, 0, stream>>>(
        S1, e2wd, e2bd, S2, 32, 64, 64, 64, 64, 64);
    conv3x3_k<128, 64, 1, 8, 32, true, false, false><<<dim3(32 * 8 * 2 * 1), blk, 0, stream>>>(
        S1, e2w1, e2b1, T5, nullptr, 32, 64, 64, 64, 64, 64);
    conv3x3_k<64, 64, 1, 8, 32, true, true, false><<<dim3(32 * 8 * 2 * 1), blk, 0, stream>>>(
        T5, e2w2, e2b2, S2, S2, 32, 64, 64, 64, 64, 64);

    // --- quantize ---
    quantize_k<<<dim3(512), blk, 0, stream>>>(S2, cb, Q);

    // --- dec0: ConvTranspose s1 (64 -> 128) == flipped 3x3 conv, ReLU ---
    conv3x3_k<64, 64, 1, 8, 32, true, false, true><<<dim3(32 * 8 * 2 * 2), blk, 0, stream>>>(
        Q, d0w, d0b, D0, nullptr, 32, 128, 64, 64, 64, 64);

    // --- dec1: ConvTranspose s2 (128 -> 64), ReLU: 64x64 -> 128x128 ---
    deconv2_k<128, 16, 4, 64, true><<<dim3(32 * 16 * 1 * 4), blk, 0, stream>>>(
        D0, d1w, d1b, D1, 32, 64, 64, 64, 128, 128);

    // --- dec2: ConvTranspose s2 (64 -> 3): 128x128 -> 256x256 ---
    deconv2_k<64, 3, 2, 128, false><<<dim3(32 * 64 * 1 * 1), blk, 0, stream>>>(
        D1, d2w, d2b, out, 32, 3, 128, 128, 256, 256);
}

// Round 2
// 4712.748 us; speedup vs baseline: 1.8580x; 1.8580x over previous
//
#include <hip/hip_runtime.h>
#include <cstddef>

// ---------------------------------------------------------------------------
// VQ-VAE forward, fp32. All convs: LDS-staged inputs (ci-chunked) + LDS-staged
// repacked weights ([ci][tap][co], co contiguous -> broadcast ds_read_b128),
// per-thread register blocking (spatial x co) so each weight float4 feeds
// 8-16 FMAs. __launch_bounds__(256,3) keeps VGPR budget at 168 (no spill).
// ---------------------------------------------------------------------------

// ======================= 3x3 conv, stride 1, pad 1 =========================
// Block tile 32x32 outputs; thread = 2x2 outputs x COC channels.
// DECONVW: weights (CIN_g, COUT, 3,3), spatially flipped (ConvTranspose s1).
template<int CIN, int CB, int COC, bool RELU, bool ADDSELF, bool DECONVW>
__launch_bounds__(256, 3)
__global__ void conv3s1_k(const float* __restrict__ in, const float* __restrict__ w,
                          const float* __restrict__ bias, float* __restrict__ out,
                          const float* __restrict__ addend,
                          int COUT, int H, int W)
{
    __shared__ float smIn[CB][34 * 34];
    __shared__ float smW[CB * 9 * COC];

    const int tid = threadIdx.x;
    int b = blockIdx.x;
    const int chunks = COUT / COC;
    const int tX = W / 32, tY = H / 32;
    const int ch = b % chunks; b /= chunks;
    const int tx = b % tX; b /= tX;
    const int ty = b % tY; const int n = b / tY;
    const int cobase = ch * COC;

    const int ty2 = tid >> 4, tx2 = tid & 15;
    const int oy0 = ty * 32 + 2 * ty2, ox0 = tx * 32 + 2 * tx2;
    const int gy0 = ty * 32 - 1, gx0 = tx * 32 - 1;

    float acc[4 * COC];
#pragma unroll
    for (int c = 0; c < COC; ++c) {
        float bb = bias[cobase + c];
        acc[c] = bb; acc[COC + c] = bb; acc[2 * COC + c] = bb; acc[3 * COC + c] = bb;
    }

    const size_t plane = (size_t)H * W;
    const float* ip0 = in + (size_t)n * CIN * plane;

    for (int ci0 = 0; ci0 < CIN; ci0 += CB) {
        __syncthreads();
        for (int idx = tid; idx < CB * 34 * 34; idx += 256) {
            int ci = idx / (34 * 34);
            int rem = idx - ci * (34 * 34);
            int r = rem / 34, c = rem - r * 34;
            int gy = gy0 + r, gx = gx0 + c;
            float v = 0.f;
            if (gy >= 0 && gy < H && gx >= 0 && gx < W)
                v = ip0[(size_t)(ci0 + ci) * plane + (size_t)gy * W + gx];
            smIn[ci][idx - ci * (34 * 34)] = v;
        }
        for (int idx = tid; idx < CB * COC; idx += 256) {
            int ci = idx % CB;
            int co = idx / CB;
#pragma unroll
            for (int k = 0; k < 9; ++k) {
                float v;
                if (DECONVW) v = w[((size_t)(ci0 + ci) * COUT + cobase + co) * 9 + (8 - k)];
                else         v = w[((size_t)(cobase + co) * CIN + ci0 + ci) * 9 + k];
                smW[(ci * 9 + k) * COC + co] = v;
            }
        }
        __syncthreads();

#pragma unroll 1
        for (int ci = 0; ci < CB; ++ci) {
            float p[16];
#pragma unroll
            for (int r = 0; r < 4; ++r)
#pragma unroll
                for (int c = 0; c < 4; ++c)
                    p[r * 4 + c] = smIn[ci][(2 * ty2 + r) * 34 + 2 * tx2 + c];
#pragma unroll
            for (int k = 0; k < 9; ++k) {
                const int ky = k / 3, kx = k % 3;
#pragma unroll
                for (int cg = 0; cg < COC / 4; ++cg) {
                    const float4 wv = *(const float4*)&smW[(ci * 9 + k) * COC + cg * 4];
#pragma unroll
                    for (int dy = 0; dy < 2; ++dy)
#pragma unroll
                        for (int dx = 0; dx < 2; ++dx) {
                            float pv = p[(dy + ky) * 4 + dx + kx];
                            float* a = &acc[(dy * 2 + dx) * COC + cg * 4];
                            a[0] = fmaf(pv, wv.x, a[0]);
                            a[1] = fmaf(pv, wv.y, a[1]);
                            a[2] = fmaf(pv, wv.z, a[2]);
                            a[3] = fmaf(pv, wv.w, a[3]);
                        }
                }
            }
        }
    }

    float* op = out + ((size_t)n * COUT + cobase) * plane;
    const float* ap = ADDSELF ? (addend + ((size_t)n * COUT + cobase) * plane) : nullptr;
#pragma unroll
    for (int c = 0; c < COC; ++c) {
#pragma unroll
        for (int dy = 0; dy < 2; ++dy) {
            float v0 = acc[(dy * 2 + 0) * COC + c];
            float v1 = acc[(dy * 2 + 1) * COC + c];
            size_t o = (size_t)c * plane + (size_t)(oy0 + dy) * W + ox0;
            if (ADDSELF) { v0 += ap[o]; v1 += ap[o + 1]; }
            if (RELU) { v0 = fmaxf(v0, 0.f); v1 = fmaxf(v1, 0.f); }
            *(float2*)&op[o] = make_float2(v0, v1);
        }
    }
}

// ======================= 3x3 conv, stride 2, pad 1 =========================
// Block tile 16x32 outputs; thread = 1x2 outputs x COC channels.
template<int CIN, int CB, int COC, bool RELU>
__launch_bounds__(256, 3)
__global__ void conv3s2_k(const float* __restrict__ in, const float* __restrict__ w,
                          const float* __restrict__ bias, float* __restrict__ out,
                          int COUT, int Hin, int Win, int Hout, int Wout)
{
    __shared__ float smIn[CB][33 * 66];
    __shared__ float smW[CB * 9 * COC];

    const int tid = threadIdx.x;
    int b = blockIdx.x;
    const int chunks = COUT / COC;
    const int tX = Wout / 32, tY = Hout / 16;
    const int ch = b % chunks; b /= chunks;
    const int tx = b % tX; b /= tX;
    const int ty = b % tY; const int n = b / tY;
    const int cobase = ch * COC;

    const int r = tid >> 4, c2 = tid & 15;
    const int oy = ty * 16 + r, ox0 = tx * 32 + 2 * c2;
    const int gy0 = ty * 32 - 1, gx0 = tx * 64 - 1;

    float acc[2 * COC];
#pragma unroll
    for (int c = 0; c < COC; ++c) {
        float bb = bias[cobase + c];
        acc[c] = bb; acc[COC + c] = bb;
    }

    const size_t plane = (size_t)Hin * Win;
    const float* ip0 = in + (size_t)n * CIN * plane;

    for (int ci0 = 0; ci0 < CIN; ci0 += CB) {
        __syncthreads();
        for (int idx = tid; idx < CB * 33 * 66; idx += 256) {
            int ci = idx / (33 * 66);
            int rem = idx - ci * (33 * 66);
            int rr = rem / 66, cc = rem - rr * 66;
            int gy = gy0 + rr, gx = gx0 + cc;
            float v = 0.f;
            if (gy >= 0 && gy < Hin && gx >= 0 && gx < Win)
                v = ip0[(size_t)(ci0 + ci) * plane + (size_t)gy * Win + gx];
            smIn[ci][rem] = v;
        }
        for (int idx = tid; idx < CB * COC; idx += 256) {
            int ci = idx % CB;
            int co = idx / CB;
#pragma unroll
            for (int k = 0; k < 9; ++k)
                smW[(ci * 9 + k) * COC + co] = w[((size_t)(cobase + co) * CIN + ci0 + ci) * 9 + k];
        }
        __syncthreads();

#pragma unroll 1
        for (int ci = 0; ci < CB; ++ci) {
            float p[15];
#pragma unroll
            for (int ky = 0; ky < 3; ++ky)
#pragma unroll
                for (int j = 0; j < 5; ++j)
                    p[ky * 5 + j] = smIn[ci][(2 * r + ky) * 66 + 4 * c2 + j];
#pragma unroll
            for (int k = 0; k < 9; ++k) {
                const int ky = k / 3, kx = k % 3;
#pragma unroll
                for (int cg = 0; cg < COC / 4; ++cg) {
                    const float4 wv = *(const float4*)&smW[(ci * 9 + k) * COC + cg * 4];
#pragma unroll
                    for (int dx = 0; dx < 2; ++dx) {
                        float pv = p[ky * 5 + 2 * dx + kx];
                        float* a = &acc[dx * COC + cg * 4];
                        a[0] = fmaf(pv, wv.x, a[0]);
                        a[1] = fmaf(pv, wv.y, a[1]);
                        a[2] = fmaf(pv, wv.z, a[2]);
                        a[3] = fmaf(pv, wv.w, a[3]);
                    }
                }
            }
        }
    }

    const size_t outPlane = (size_t)Hout * Wout;
    float* op = out + ((size_t)n * COUT + cobase) * outPlane + (size_t)oy * Wout + ox0;
#pragma unroll
    for (int c = 0; c < COC; ++c) {
        float v0 = acc[c], v1 = acc[COC + c];
        if (RELU) { v0 = fmaxf(v0, 0.f); v1 = fmaxf(v1, 0.f); }
        *(float2*)&op[(size_t)c * outPlane] = make_float2(v0, v1);
    }
}

// ============================ 1x1 conv, stride S ===========================
// Whole weight chunk in LDS; thread = 2 positions x COC channels.
template<int CIN, int COC, int S, bool RELU>
__launch_bounds__(256, 4)
__global__ void conv1x1_k(const float* __restrict__ in, const float* __restrict__ w,
                          const float* __restrict__ bias, float* __restrict__ out,
                          int COUT, int Hin, int Win, int Hout, int Wout)
{
    __shared__ float smW[CIN * COC];
    const int tid = threadIdx.x;
    int b = blockIdx.x;
    const int chunks = COUT / COC;
    const int spB = (Hout * Wout) / 512;
    const int sb = b % spB; b /= spB;
    const int ch = b % chunks; const int n = b / chunks;
    const int cobase = ch * COC;

    for (int idx = tid; idx < CIN * COC; idx += 256) {
        int co = idx / CIN, ci = idx - co * CIN;
        smW[ci * COC + co] = w[(size_t)(cobase + co) * CIN + ci];
    }
    __syncthreads();

    const int pos0 = sb * 512 + 2 * tid;
    const int oy = pos0 / Wout, ox = pos0 - oy * Wout;

    float acc[2 * COC];
#pragma unroll
    for (int c = 0; c < COC; ++c) {
        float bb = bias[cobase + c];
        acc[c] = bb; acc[COC + c] = bb;
    }

    const size_t inPlane = (size_t)Hin * Win;
    const float* ip = in + (size_t)n * CIN * inPlane + (size_t)(oy * S) * Win + (size_t)(ox * S);
#pragma unroll 1
    for (int ci = 0; ci < CIN; ++ci) {
        float i0 = ip[(size_t)ci * inPlane];
        float i1 = ip[(size_t)ci * inPlane + S];
#pragma unroll
        for (int cg = 0; cg < COC / 4; ++cg) {
            const float4 wv = *(const float4*)&smW[ci * COC + cg * 4];
            float* a0 = &acc[cg * 4];
            float* a1 = &acc[COC + cg * 4];
            a0[0] = fmaf(i0, wv.x, a0[0]); a0[1] = fmaf(i0, wv.y, a0[1]);
            a0[2] = fmaf(i0, wv.z, a0[2]); a0[3] = fmaf(i0, wv.w, a0[3]);
            a1[0] = fmaf(i1, wv.x, a1[0]); a1[1] = fmaf(i1, wv.y, a1[1]);
            a1[2] = fmaf(i1, wv.z, a1[2]); a1[3] = fmaf(i1, wv.w, a1[3]);
        }
    }
    const size_t outPlane = (size_t)Hout * Wout;
    float* op = out + ((size_t)n * COUT + cobase) * outPlane + pos0;
#pragma unroll
    for (int c = 0; c < COC; ++c) {
        float v0 = acc[c], v1 = acc[COC + c];
        if (RELU) { v0 = fmaxf(v0, 0.f); v1 = fmaxf(v1, 0.f); }
        *(float2*)&op[(size_t)c * outPlane] = make_float2(v0, v1);
    }
}

// ==================== ConvTranspose2d k3 s2 p1 op1 =========================
// Thread = NQY x NQX quads (each quad = 2x2 outputs) x COC channels.
// w: (CIN_g, COUT, 3, 3) PyTorch layout. COUTR = real out channels (<= COC*chunks).
template<int CIN, int CB, int COC, int NQY, int NQX, bool RELU>
__launch_bounds__(256, 3)
__global__ void deconv2_k(const float* __restrict__ in, const float* __restrict__ w,
                          const float* __restrict__ bias, float* __restrict__ out,
                          int COUT, int COUTR, int Hin, int Win, int Hout, int Wout)
{
    constexpr int RH = 16 * NQY + 1;
    constexpr int RW = 16 * NQX + 2;   // +1 halo, +1 pad (even stride)
    __shared__ float smIn[CB][RH * RW];
    __shared__ float smW[CB * 9 * COC];

    const int tid = threadIdx.x;
    int b = blockIdx.x;
    const int chunks = COUT / COC;
    const int tX = Wout / (32 * NQX), tY = Hout / (32 * NQY);
    const int ch = b % chunks; b /= chunks;
    const int tx = b % tX; b /= tX;
    const int ty = b % tY; const int n = b / tY;
    const int cobase = ch * COC;

    const int tqy = tid >> 4, tqx = tid & 15;
    const int qby = ty * (16 * NQY), qbx = tx * (16 * NQX);   // input-space origin
    const int ry0 = tqy * NQY, rx0 = tqx * NQX;

    float acc[NQY * NQX * 4 * COC];
#pragma unroll
    for (int c = 0; c < COC; ++c) {
        float bb = (cobase + c < COUTR) ? bias[cobase + c] : 0.f;
#pragma unroll
        for (int qp = 0; qp < NQY * NQX * 4; ++qp) acc[qp * COC + c] = bb;
    }

    const size_t plane = (size_t)Hin * Win;
    const float* ip0 = in + (size_t)n * CIN * plane;

    for (int ci0 = 0; ci0 < CIN; ci0 += CB) {
        __syncthreads();
        for (int idx = tid; idx < CB * RH * RW; idx += 256) {
            int ci = idx / (RH * RW);
            int rem = idx - ci * (RH * RW);
            int rr = rem / RW, cc = rem - rr * RW;
            int gy = qby + rr, gx = qbx + cc;
            float v = 0.f;
            if (gy < Hin && gx < Win)
                v = ip0[(size_t)(ci0 + ci) * plane + (size_t)gy * Win + gx];
            smIn[ci][rem] = v;
        }
        for (int idx = tid; idx < CB * COC; idx += 256) {
            int ci = idx % CB;
            int co = idx / CB;
#pragma unroll
            for (int k = 0; k < 9; ++k) {
                float v = 0.f;
                if (cobase + co < COUTR)
                    v = w[((size_t)(ci0 + ci) * COUTR + cobase + co) * 9 + k];
                smW[(ci * 9 + k) * COC + co] = v;
            }
        }
        __syncthreads();

#pragma unroll 1
        for (int ci = 0; ci < CB; ++ci) {
            float p[(NQY + 1) * (NQX + 1)];
#pragma unroll
            for (int i = 0; i <= NQY; ++i)
#pragma unroll
                for (int j = 0; j <= NQX; ++j)
                    p[i * (NQX + 1) + j] = smIn[ci][(ry0 + i) * RW + rx0 + j];
#pragma unroll
            for (int k = 0; k < 9; ++k) {
                const int ky = k / 3, kx = k % 3;
                const int dy = (ky == 1) ? 0 : 1, sy = (ky == 0) ? 1 : 0;
                const int dx = (kx == 1) ? 0 : 1, sx = (kx == 0) ? 1 : 0;
#pragma unroll
                for (int cg = 0; cg < COC / 4; ++cg) {
                    const float4 wv = *(const float4*)&smW[(ci * 9 + k) * COC + cg * 4];
#pragma unroll
                    for (int iy = 0; iy < NQY; ++iy)
#pragma unroll
                        for (int ix = 0; ix < NQX; ++ix) {
                            float pv = p[(iy + sy) * (NQX + 1) + ix + sx];
                            float* a = &acc[((iy * NQX + ix) * 4 + dy * 2 + dx) * COC + cg * 4];
                            a[0] = fmaf(pv, wv.x, a[0]);
                            a[1] = fmaf(pv, wv.y, a[1]);
                            a[2] = fmaf(pv, wv.z, a[2]);
                            a[3] = fmaf(pv, wv.w, a[3]);
                        }
                }
            }
        }
    }

    const size_t outPlane = (size_t)Hout * Wout;
#pragma unroll
    for (int c = 0; c < COC; ++c) {
        if (cobase + c >= COUTR) break;
        float* op = out + ((size_t)n * COUTR + cobase + c) * outPlane;
#pragma unroll
        for (int iy = 0; iy < NQY; ++iy) {
            const int oy = 2 * (qby + ry0 + iy);
#pragma unroll
            for (int a2 = 0; a2 < 2; ++a2) {
                float4 v;
                float* vp = (float*)&v;
#pragma unroll
                for (int ix = 0; ix < NQX; ++ix) {
                    float u0 = acc[((iy * NQX + ix) * 4 + a2 * 2 + 0) * COC + c];
                    float u1 = acc[((iy * NQX + ix) * 4 + a2 * 2 + 1) * COC + c];
                    if (RELU) { u0 = fmaxf(u0, 0.f); u1 = fmaxf(u1, 0.f); }
                    vp[2 * ix] = u0; vp[2 * ix + 1] = u1;
                }
                if (NQX == 2) {
                    *(float4*)&op[(size_t)(oy + a2) * Wout + 2 * (qbx + rx0)] = v;
                } else {
                    *(float2*)&op[(size_t)(oy + a2) * Wout + 2 * (qbx + rx0)] = make_float2(vp[0], vp[1]);
                }
            }
        }
    }
}

// ============================== quantize ===================================
__launch_bounds__(256)
__global__ void quantize_k(const float* __restrict__ h, const float* __restrict__ cb,
                           float* __restrict__ q)
{
    __shared__ float cn[512];
    __shared__ float cbl[128 * 64];
    const int tid = threadIdx.x;

    for (int i = tid; i < 512; i += 256) {
        float s = 0.f;
#pragma unroll
        for (int j = 0; j < 64; ++j) { float v = cb[i * 64 + j]; s = fmaf(v, v, s); }
        cn[i] = s;
    }

    const int t = blockIdx.x * 256 + tid;
    const int n = t >> 12, rem = t & 4095;
    const float* hp = h + (size_t)n * 64 * 4096 + rem;
    float e[64];
#pragma unroll
    for (int j = 0; j < 64; ++j) e[j] = hp[(size_t)j * 4096];

    float best = 3.4e38f; int bi = 0;
    for (int chn = 0; chn < 4; ++chn) {
        __syncthreads();
        const float4* src = reinterpret_cast<const float4*>(cb + chn * 128 * 64);
        float4* dst = reinterpret_cast<float4*>(cbl);
        for (int i = tid; i < 128 * 64 / 4; i += 256) dst[i] = src[i];
        __syncthreads();
        for (int c = 0; c < 128; ++c) {
            float dot = 0.f;
#pragma unroll
            for (int j = 0; j < 64; ++j) dot = fmaf(e[j], cbl[c * 64 + j], dot);
            float d = cn[chn * 128 + c] - 2.f * dot;
            if (d < best) { best = d; bi = chn * 128 + c; }
        }
    }

    const float* crow = cb + (size_t)bi * 64;
    float* qp = q + (size_t)n * 64 * 4096 + rem;
#pragma unroll
    for (int j = 0; j < 64; ++j) qp[(size_t)j * 4096] = crow[j];
}

extern "C" void kernel_launch(void* const* d_in, const int* in_sizes, int n_in,
                              void* d_out, int out_size, void* d_ws, size_t ws_size,
                              hipStream_t stream)
{
    const float* x    = (const float*)d_in[0];
    const float* e0w1 = (const float*)d_in[1];  const float* e0b1 = (const float*)d_in[2];
    const float* e0w2 = (const float*)d_in[3];  const float* e0b2 = (const float*)d_in[4];
    const float* e0wd = (const float*)d_in[5];  const float* e0bd = (const float*)d_in[6];
    const float* e1w1 = (const float*)d_in[7];  const float* e1b1 = (const float*)d_in[8];
    const float* e1w2 = (const float*)d_in[9];  const float* e1b2 = (const float*)d_in[10];
    const float* e1wd = (const float*)d_in[11]; const float* e1bd = (const float*)d_in[12];
    const float* e2w1 = (const float*)d_in[13]; const float* e2b1 = (const float*)d_in[14];
    const float* e2w2 = (const float*)d_in[15]; const float* e2b2 = (const float*)d_in[16];
    const float* e2wd = (const float*)d_in[17]; const float* e2bd = (const float*)d_in[18];
    const float* d0w  = (const float*)d_in[19]; const float* d0b  = (const float*)d_in[20];
    const float* d1w  = (const float*)d_in[21]; const float* d1b  = (const float*)d_in[22];
    const float* d2w  = (const float*)d_in[23]; const float* d2b  = (const float*)d_in[24];
    const float* cb   = (const float*)d_in[25];
    float* out = (float*)d_out;

    float* R0 = (float*)d_ws;
    float* R1 = R0 + 33554432;

    float* S0 = R1;                 // enc0 out (32,64,128,128)
    float* T1 = R0;                 // enc0 conv1 out
    float* S1 = R0;                 // enc1 out (32,128,64,64)
    float* T3 = R0 + 16777216;      // enc1 conv1 out
    float* S2 = R1;                 // enc2 out (32,64,64,64)
    float* T5 = R1 + 8388608;       // enc2 conv1 out
    float* Q  = R0;                 // quantized (32,64,64,64)
    float* D0 = R0 + 16777216;      // dec0 out (32,128,64,64)
    float* D1 = R1;                 // dec1 out (32,64,128,128)

    dim3 blk(256);

    // --- enc0 (3 -> 64, stride 2): 256 -> 128 ---
    conv1x1_k<3, 32, 2, false><<<dim3(32 * 2 * 32), blk, 0, stream>>>(
        x, e0wd, e0bd, S0, 64, 256, 256, 128, 128);
    conv3s2_k<3, 3, 32, true><<<dim3(32 * 2 * 8 * 4), blk, 0, stream>>>(
        x, e0w1, e0b1, T1, 64, 256, 256, 128, 128);
    conv3s1_k<64, 8, 16, true, true, false><<<dim3(32 * 4 * 4 * 4), blk, 0, stream>>>(
        T1, e0w2, e0b2, S0, S0, 64, 128, 128);

    // --- enc1 (64 -> 128, stride 2): 128 -> 64 ---
    conv1x1_k<64, 32, 2, false><<<dim3(32 * 4 * 8), blk, 0, stream>>>(
        S0, e1wd, e1bd, S1, 128, 128, 128, 64, 64);
    conv3s2_k<64, 4, 32, true><<<dim3(32 * 4 * 4 * 2), blk, 0, stream>>>(
        S0, e1w1, e1b1, T3, 128, 128, 128, 64, 64);
    conv3s1_k<128, 8, 16, true, true, false><<<dim3(32 * 8 * 2 * 2), blk, 0, stream>>>(
        T3, e1w2, e1b2, S1, S1, 128, 64, 64);

    // --- enc2 (128 -> 64, stride 1) ---
    conv1x1_k<128, 32, 1, false><<<dim3(32 * 2 * 8), blk, 0, stream>>>(
        S1, e2wd, e2bd, S2, 64, 64, 64, 64, 64);
    conv3s1_k<128, 8, 16, true, false, false><<<dim3(32 * 4 * 2 * 2), blk, 0, stream>>>(
        S1, e2w1, e2b1, T5, nullptr, 64, 64, 64);
    conv3s1_k<64, 8, 16, true, true, false><<<dim3(32 * 4 * 2 * 2), blk, 0, stream>>>(
        T5, e2w2, e2b2, S2, S2, 64, 64, 64);

    // --- quantize ---
    quantize_k<<<dim3(512), blk, 0, stream>>>(S2, cb, Q);

    // --- dec0: ConvTranspose s1 (64 -> 128) == flipped conv, ReLU ---
    conv3s1_k<64, 8, 16, true, false, true><<<dim3(32 * 8 * 2 * 2), blk, 0, stream>>>(
        Q, d0w, d0b, D0, nullptr, 128, 64, 64);

    // --- dec1: ConvTranspose s2 (128 -> 64), ReLU: 64 -> 128 ---
    deconv2_k<128, 16, 8, 1, 2, true><<<dim3(32 * 8 * 2 * 4), blk, 0, stream>>>(
        D0, d1w, d1b, D1, 64, 64, 64, 64, 128, 128);

    // --- dec2: ConvTranspose s2 (64 -> 3): 128 -> 256 ---
    deconv2_k<64, 8, 4, 2, 2, false><<<dim3(32 * 1 * 4 * 4), blk, 0, stream>>>(
        D1, d2w, d2b, out, 4, 3, 128, 128, 256, 256);
}

// Round 3
// 3332.156 us; speedup vs baseline: 2.6279x; 1.4143x over previous
//
#include <hip/hip_runtime.h>
#include <cstddef>

// ---------------------------------------------------------------------------
// VQ-VAE forward, fp32 direct conv. Round 3: spill-proof float4 accumulators,
// pre-packed weights [ci][k][co] (broadcast ds_read_b128), 2 outputs/thread.
// ---------------------------------------------------------------------------

typedef float v4f __attribute__((ext_vector_type(4)));

__device__ __forceinline__ void fma4(v4f& a, float p, const v4f& w) {
    a.x = fmaf(p, w.x, a.x); a.y = fmaf(p, w.y, a.y);
    a.z = fmaf(p, w.z, a.z); a.w = fmaf(p, w.w, a.w);
}

// Repack conv/deconv weights to [ci][9][cout] (cout padded, zero-filled).
// conv  src: (coutR, cin, 3, 3);  deconv src: (cin, coutR, 3, 3).
__global__ void repack_k(const float* __restrict__ src, float* __restrict__ dst,
                         int cout, int coutR, int cin, int flip, int deconv)
{
    int t = blockIdx.x * 256 + threadIdx.x;
    int tot = cin * 9 * cout;
    if (t >= tot) return;
    int co = t % cout; int k = (t / cout) % 9; int ci = t / (9 * cout);
    float v = 0.f;
    if (co < coutR) {
        int ks = flip ? 8 - k : k;
        v = deconv ? src[((size_t)ci * coutR + co) * 9 + ks]
                   : src[((size_t)co * cin + ci) * 9 + ks];
    }
    dst[t] = v;
}

// ===================== 3x3 conv s1 p1 — tile 16x32, 2 out/thread ============
template<int CIN, int CB, bool RELU, bool ADDSELF>
__launch_bounds__(256, 4)
__global__ void conv3s1_k(const float* __restrict__ in, const float* __restrict__ wp,
                          const float* __restrict__ bias, float* __restrict__ out,
                          const float* __restrict__ addend, int COUT, int H, int W)
{
    constexpr int COC = 32;
    __shared__ float smIn[CB * 612];            // 18 x 34
    __shared__ float smW[CB * 9 * COC];
    const int tid = threadIdx.x;
    int b = blockIdx.x;
    const int chunks = COUT / COC;
    const int tX = W / 32, tY = H / 16;
    const int ch = b % chunks; b /= chunks;
    const int tx = b % tX; b /= tX;
    const int ty = b % tY; const int n = b / tY;
    const int cobase = ch * COC;
    const int r = tid >> 4, c = tid & 15;
    const int gy0 = ty * 16 - 1, gx0 = tx * 32 - 1;

    v4f acc[16];
#pragma unroll
    for (int g = 0; g < 8; ++g) {
        v4f bv = *(const v4f*)&bias[cobase + 4 * g];
        acc[g] = bv; acc[8 + g] = bv;
    }

    const size_t plane = (size_t)H * W;
    const float* ip0 = in + (size_t)n * CIN * plane;
    const float* wp0 = wp + cobase;

    for (int ci0 = 0; ci0 < CIN; ci0 += CB) {
        __syncthreads();
        for (int idx = tid; idx < CB * 612; idx += 256) {
            int ci = idx / 612, rem = idx - ci * 612;
            int rr = rem / 34, cc = rem - rr * 34;
            int gy = gy0 + rr, gx = gx0 + cc;
            float v = 0.f;
            if (gy >= 0 && gy < H && gx >= 0 && gx < W)
                v = ip0[(size_t)(ci0 + ci) * plane + (size_t)gy * W + gx];
            smIn[idx] = v;
        }
        for (int idx = tid; idx < CB * 9 * COC; idx += 256) {
            int q = idx / COC, co = idx - q * COC;
            smW[idx] = wp0[((size_t)ci0 * 9 + q) * COUT + co];
        }
        __syncthreads();

#pragma unroll 1
        for (int ci = 0; ci < CB; ++ci) {
            float p[12];
            const float* sp = &smIn[ci * 612 + r * 34 + 2 * c];
#pragma unroll
            for (int i = 0; i < 3; ++i)
#pragma unroll
                for (int j = 0; j < 4; ++j)
                    p[i * 4 + j] = sp[i * 34 + j];
            const float* wrow = &smW[ci * 9 * COC];
#pragma unroll
            for (int k = 0; k < 9; ++k) {
                const int ky = k / 3, kx = k % 3;
#pragma unroll
                for (int g = 0; g < 8; ++g) {
                    v4f wv = *(const v4f*)&wrow[k * COC + 4 * g];
                    fma4(acc[g],     p[ky * 4 + kx],     wv);
                    fma4(acc[8 + g], p[ky * 4 + kx + 1], wv);
                }
            }
        }
    }

    const int oy = ty * 16 + r, ox = tx * 32 + 2 * c;
    float* op = out + ((size_t)n * COUT + cobase) * plane + (size_t)oy * W + ox;
    const float* ap = ADDSELF ? addend + ((size_t)n * COUT + cobase) * plane + (size_t)oy * W + ox
                              : nullptr;
#pragma unroll
    for (int g = 0; g < 8; ++g) {
#pragma unroll
        for (int e = 0; e < 4; ++e) {
            float v0 = acc[g][e], v1 = acc[8 + g][e];
            size_t o = (size_t)(4 * g + e) * plane;
            if (ADDSELF) { float2 adn = *(const float2*)&ap[o]; v0 += adn.x; v1 += adn.y; }
            if (RELU) { v0 = fmaxf(v0, 0.f); v1 = fmaxf(v1, 0.f); }
            *(float2*)&op[o] = make_float2(v0, v1);
        }
    }
}

// ===================== 3x3 conv s2 p1 — tile 16x32 out, 2 out/thread ========
template<int CIN, int CB, bool RELU>
__launch_bounds__(256, 4)
__global__ void conv3s2_k(const float* __restrict__ in, const float* __restrict__ wp,
                          const float* __restrict__ bias, float* __restrict__ out,
                          int COUT, int Hin, int Win)
{
    constexpr int COC = 32;
    __shared__ float smIn[CB * 2178];           // 33 x 66
    __shared__ float smW[CB * 9 * COC];
    const int Hout = Hin >> 1, Wout = Win >> 1;
    const int tid = threadIdx.x;
    int b = blockIdx.x;
    const int chunks = COUT / COC;
    const int tX = Wout / 32, tY = Hout / 16;
    const int ch = b % chunks; b /= chunks;
    const int tx = b % tX; b /= tX;
    const int ty = b % tY; const int n = b / tY;
    const int cobase = ch * COC;
    const int r = tid >> 4, c = tid & 15;
    const int gy0 = ty * 32 - 1, gx0 = tx * 64 - 1;

    v4f acc[16];
#pragma unroll
    for (int g = 0; g < 8; ++g) {
        v4f bv = *(const v4f*)&bias[cobase + 4 * g];
        acc[g] = bv; acc[8 + g] = bv;
    }

    const size_t plane = (size_t)Hin * Win;
    const float* ip0 = in + (size_t)n * CIN * plane;
    const float* wp0 = wp + cobase;

    for (int ci0 = 0; ci0 < CIN; ci0 += CB) {
        __syncthreads();
        for (int idx = tid; idx < CB * 2178; idx += 256) {
            int ci = idx / 2178, rem = idx - ci * 2178;
            int rr = rem / 66, cc = rem - rr * 66;
            int gy = gy0 + rr, gx = gx0 + cc;
            float v = 0.f;
            if (gy >= 0 && gy < Hin && gx >= 0 && gx < Win)
                v = ip0[(size_t)(ci0 + ci) * plane + (size_t)gy * Win + gx];
            smIn[idx] = v;
        }
        for (int idx = tid; idx < CB * 9 * COC; idx += 256) {
            int q = idx / COC, co = idx - q * COC;
            smW[idx] = wp0[((size_t)ci0 * 9 + q) * COUT + co];
        }
        __syncthreads();

#pragma unroll 1
        for (int ci = 0; ci < CB; ++ci) {
            float p[15];
            const float* sp = &smIn[ci * 2178 + 2 * r * 66 + 4 * c];
#pragma unroll
            for (int i = 0; i < 3; ++i)
#pragma unroll
                for (int j = 0; j < 5; ++j)
                    p[i * 5 + j] = sp[i * 66 + j];
            const float* wrow = &smW[ci * 9 * COC];
#pragma unroll
            for (int k = 0; k < 9; ++k) {
                const int ky = k / 3, kx = k % 3;
#pragma unroll
                for (int g = 0; g < 8; ++g) {
                    v4f wv = *(const v4f*)&wrow[k * COC + 4 * g];
                    fma4(acc[g],     p[ky * 5 + kx],     wv);
                    fma4(acc[8 + g], p[ky * 5 + kx + 2], wv);
                }
            }
        }
    }

    const size_t outPlane = (size_t)Hout * Wout;
    const int oy = ty * 16 + r, ox = tx * 32 + 2 * c;
    float* op = out + ((size_t)n * COUT + cobase) * outPlane + (size_t)oy * Wout + ox;
#pragma unroll
    for (int g = 0; g < 8; ++g) {
#pragma unroll
        for (int e = 0; e < 4; ++e) {
            float v0 = acc[g][e], v1 = acc[8 + g][e];
            if (RELU) { v0 = fmaxf(v0, 0.f); v1 = fmaxf(v1, 0.f); }
            *(float2*)&op[(size_t)(4 * g + e) * outPlane] = make_float2(v0, v1);
        }
    }
}

// =========== ConvTranspose k3 s2 p1 op1 — 2 quads/thread, COC channels ======
template<int CIN, int CB, int COC, bool RELU>
__launch_bounds__(256, 3)
__global__ void deconv2_k(const float* __restrict__ in, const float* __restrict__ wp,
                          const float* __restrict__ bias, float* __restrict__ out,
                          int COUTR, int COUTP, int Hin, int Win)
{
    constexpr int RW = 33, RH = 17;             // 16x32-quad tile + halo
    __shared__ float smIn[CB * RH * RW];
    __shared__ float smW[CB * 9 * COC];
    const int Wout = Win * 2;
    const int tid = threadIdx.x;
    int b = blockIdx.x;
    const int chunks = COUTP / COC;
    const int qTX = Win / 32, qTY = Hin / 16;
    const int ch = b % chunks; b /= chunks;
    const int qtx = b % qTX; b /= qTX;
    const int qty = b % qTY; const int n = b / qTY;
    const int cobase = ch * COC;
    const int tqy = tid >> 4, tqx = tid & 15;
    const int qby = qty * 16, qbx = qtx * 32;

    v4f acc[8 * COC / 4];                        // 2 quads x 4 pts x COC
#pragma unroll
    for (int g = 0; g < COC / 4; ++g) {
        v4f bv;
#pragma unroll
        for (int e = 0; e < 4; ++e)
            bv[e] = (cobase + 4 * g + e < COUTR) ? bias[cobase + 4 * g + e] : 0.f;
#pragma unroll
        for (int pt = 0; pt < 8; ++pt) acc[pt * (COC / 4) + g] = bv;
    }

    const size_t plane = (size_t)Hin * Win;
    const float* ip0 = in + (size_t)n * CIN * plane;
    const float* wp0 = wp + cobase;

    for (int ci0 = 0; ci0 < CIN; ci0 += CB) {
        __syncthreads();
        for (int idx = tid; idx < CB * RH * RW; idx += 256) {
            int ci = idx / (RH * RW), rem = idx - ci * (RH * RW);
            int rr = rem / RW, cc = rem - rr * RW;
            int gy = qby + rr, gx = qbx + cc;
            float v = 0.f;
            if (gy < Hin && gx < Win)
                v = ip0[(size_t)(ci0 + ci) * plane + (size_t)gy * Win + gx];
            smIn[idx] = v;
        }
        for (int idx = tid; idx < CB * 9 * COC; idx += 256) {
            int q = idx / COC, co = idx - q * COC;
            smW[idx] = wp0[((size_t)ci0 * 9 + q) * COUTP + co];
        }
        __syncthreads();

#pragma unroll 1
        for (int ci = 0; ci < CB; ++ci) {
            float p[6];                          // rows 2 x cols 3 (2 quads + halo)
            const float* sp = &smIn[ci * RH * RW + tqy * RW + 2 * tqx];
#pragma unroll
            for (int i = 0; i < 2; ++i)
#pragma unroll
                for (int j = 0; j < 3; ++j)
                    p[i * 3 + j] = sp[i * RW + j];
            const float* wrow = &smW[ci * 9 * COC];
#pragma unroll
            for (int k = 0; k < 9; ++k) {
                const int ky = k / 3, kx = k % 3;
                const int dy = (ky == 1) ? 0 : 1, iy = (ky == 0) ? 1 : 0;
                const int dx = (kx == 1) ? 0 : 1, ix = (kx == 0) ? 1 : 0;
#pragma unroll
                for (int g = 0; g < COC / 4; ++g) {
                    v4f wv = *(const v4f*)&wrow[k * COC + 4 * g];
                    fma4(acc[(0 + dy * 2 + dx) * (COC / 4) + g], p[iy * 3 + ix],     wv);
                    fma4(acc[(4 + dy * 2 + dx) * (COC / 4) + g], p[iy * 3 + ix + 1], wv);
                }
            }
        }
    }

    const size_t oPlane = (size_t)(Hin * 2) * Wout;
    const int oy = 2 * (qby + tqy), ox = 2 * (qbx + 2 * tqx);
#pragma unroll
    for (int g = 0; g < COC / 4; ++g) {
#pragma unroll
        for (int e = 0; e < 4; ++e) {
            int cch = cobase + 4 * g + e;
            if (cch >= COUTR) break;
            float* op = out + ((size_t)n * COUTR + cch) * oPlane + (size_t)oy * Wout + ox;
#pragma unroll
            for (int a2 = 0; a2 < 2; ++a2) {     // output row pair
                float u0 = acc[(0 + a2 * 2 + 0) * (COC / 4) + g][e];
                float u1 = acc[(0 + a2 * 2 + 1) * (COC / 4) + g][e];
                float u2 = acc[(4 + a2 * 2 + 0) * (COC / 4) + g][e];
                float u3 = acc[(4 + a2 * 2 + 1) * (COC / 4) + g][e];
                if (RELU) { u0 = fmaxf(u0, 0.f); u1 = fmaxf(u1, 0.f);
                            u2 = fmaxf(u2, 0.f); u3 = fmaxf(u3, 0.f); }
                *(float4*)&op[(size_t)a2 * Wout] = make_float4(u0, u1, u2, u3);
            }
        }
    }
}

// ===================== 1x1 conv stride S — 1 pos/thread, 32 co ==============
template<int CIN, int S, bool RELU>
__launch_bounds__(256, 4)
__global__ void conv1x1_k(const float* __restrict__ in, const float* __restrict__ w,
                          const float* __restrict__ bias, float* __restrict__ out,
                          int COUT, int Hin, int Win, int Hout, int Wout)
{
    constexpr int COC = 32;
    __shared__ float smW[CIN * COC];
    const int tid = threadIdx.x;
    int b = blockIdx.x;
    const int chunks = COUT / COC;
    const int spB = (Hout * Wout) / 256;
    const int ch = b % chunks; b /= chunks;
    const int sb = b % spB; const int n = b / spB;
    const int cobase = ch * COC;

    for (int idx = tid; idx < CIN * COC; idx += 256) {
        int ci = idx / COC, co = idx - ci * COC;
        smW[idx] = w[(size_t)(cobase + co) * CIN + ci];
    }
    __syncthreads();

    const int pos = sb * 256 + tid;
    const int oy = pos / Wout, ox = pos - oy * Wout;

    v4f acc[8];
#pragma unroll
    for (int g = 0; g < 8; ++g) acc[g] = *(const v4f*)&bias[cobase + 4 * g];

    const size_t inPlane = (size_t)Hin * Win;
    const float* ip = in + (size_t)n * CIN * inPlane + (size_t)(oy * S) * Win + (size_t)(ox * S);
#pragma unroll 1
    for (int ci = 0; ci < CIN; ++ci) {
        float v = ip[(size_t)ci * inPlane];
#pragma unroll
        for (int g = 0; g < 8; ++g)
            fma4(acc[g], v, *(const v4f*)&smW[ci * COC + 4 * g]);
    }
    const size_t outPlane = (size_t)Hout * Wout;
    float* op = out + ((size_t)n * COUT + cobase) * outPlane + pos;
#pragma unroll
    for (int g = 0; g < 8; ++g)
#pragma unroll
        for (int e = 0; e < 4; ++e) {
            float v = acc[g][e];
            if (RELU) v = fmaxf(v, 0.f);
            op[(size_t)(4 * g + e) * outPlane] = v;
        }
}

// ============================== quantize ===================================
__launch_bounds__(256)
__global__ void quantize_k(const float* __restrict__ h, const float* __restrict__ cb,
                           float* __restrict__ q)
{
    __shared__ float cn[512];
    __shared__ float cbl[128 * 64];
    const int tid = threadIdx.x;

    for (int i = tid; i < 512; i += 256) {
        float s = 0.f;
#pragma unroll
        for (int j = 0; j < 64; ++j) { float v = cb[i * 64 + j]; s = fmaf(v, v, s); }
        cn[i] = s;
    }

    const int t = blockIdx.x * 256 + tid;
    const int n = t >> 12, rem = t & 4095;
    const float* hp = h + (size_t)n * 64 * 4096 + rem;
    float e[64];
#pragma unroll
    for (int j = 0; j < 64; ++j) e[j] = hp[(size_t)j * 4096];

    float best = 3.4e38f; int bi = 0;
    for (int chn = 0; chn < 4; ++chn) {
        __syncthreads();
        const float4* src = reinterpret_cast<const float4*>(cb + chn * 128 * 64);
        float4* dst = reinterpret_cast<float4*>(cbl);
        for (int i = tid; i < 128 * 64 / 4; i += 256) dst[i] = src[i];
        __syncthreads();
        for (int c = 0; c < 128; ++c) {
            float dot = 0.f;
#pragma unroll
            for (int j = 0; j < 64; ++j) dot = fmaf(e[j], cbl[c * 64 + j], dot);
            float d = cn[chn * 128 + c] - 2.f * dot;
            if (d < best) { best = d; bi = chn * 128 + c; }
        }
    }

    const float* crow = cb + (size_t)bi * 64;
    float* qp = q + (size_t)n * 64 * 4096 + rem;
#pragma unroll
    for (int j = 0; j < 64; ++j) qp[(size_t)j * 4096] = crow[j];
}

extern "C" void kernel_launch(void* const* d_in, const int* in_sizes, int n_in,
                              void* d_out, int out_size, void* d_ws, size_t ws_size,
                              hipStream_t stream)
{
    const float* x    = (const float*)d_in[0];
    const float* e0w1 = (const float*)d_in[1];  const float* e0b1 = (const float*)d_in[2];
    const float* e0w2 = (const float*)d_in[3];  const float* e0b2 = (const float*)d_in[4];
    const float* e0wd = (const float*)d_in[5];  const float* e0bd = (const float*)d_in[6];
    const float* e1w1 = (const float*)d_in[7];  const float* e1b1 = (const float*)d_in[8];
    const float* e1w2 = (const float*)d_in[9];  const float* e1b2 = (const float*)d_in[10];
    const float* e1wd = (const float*)d_in[11]; const float* e1bd = (const float*)d_in[12];
    const float* e2w1 = (const float*)d_in[13]; const float* e2b1 = (const float*)d_in[14];
    const float* e2w2 = (const float*)d_in[15]; const float* e2b2 = (const float*)d_in[16];
    const float* e2wd = (const float*)d_in[17]; const float* e2bd = (const float*)d_in[18];
    const float* d0w  = (const float*)d_in[19]; const float* d0b  = (const float*)d_in[20];
    const float* d1w  = (const float*)d_in[21]; const float* d1b  = (const float*)d_in[22];
    const float* d2w  = (const float*)d_in[23]; const float* d2b  = (const float*)d_in[24];
    const float* cb   = (const float*)d_in[25];
    float* out = (float*)d_out;
    float* ws  = (float*)d_ws;

    // packed weights in d_out's slack (d_out overwritten only by final dec2)
    float* P_e0w1 = out + 0;
    float* P_e0w2 = out + 1728;
    float* P_e1w1 = out + 38592;
    float* P_e1w2 = out + 112320;
    float* P_e2w1 = out + 259776;
    float* P_e2w2 = out + 333504;
    float* P_d0w  = out + 370368;
    float* P_d1w  = ws + 50331648;     // packed AFTER enc1 conv2 (old T3 zone)
    float* P_d2w  = ws + 33554432;     // packed AFTER dec1 (old D0 zone)

    // ws activation layout (floats), exact-fit liveness plan:
    float* S0  = ws;                   // [0, 33554432)
    float* T1h = ws + 33554432;        // half-batch enc0 intermediate
    float* S1  = ws + 33554432;        // reuses T1h region
    float* T3  = ws + 50331648;        // [50331648, 67108864)
    float* S2  = ws;                   // [0, 8388608)
    float* T5  = ws + 8388608;
    float* Q   = ws + 16777216;
    float* D0  = ws + 33554432;
    float* D1  = ws;

    dim3 blk(256);
    auto rp = [&](const float* src, float* dst, int cout, int coutR, int cin, int flip, int dec) {
        int tot = cin * 9 * cout;
        repack_k<<<dim3((tot + 255) / 256), blk, 0, stream>>>(src, dst, cout, coutR, cin, flip, dec);
    };

    rp(e0w1, P_e0w1, 64, 64, 3, 0, 0);
    rp(e0w2, P_e0w2, 64, 64, 64, 0, 0);
    rp(e1w1, P_e1w1, 128, 128, 64, 0, 0);
    rp(e1w2, P_e1w2, 128, 128, 128, 0, 0);
    rp(e2w1, P_e2w1, 64, 64, 128, 0, 0);
    rp(e2w2, P_e2w2, 64, 64, 64, 0, 0);
    rp(d0w,  P_d0w, 128, 128, 64, 1, 1);        // ConvT s1 == flipped conv

    // --- enc0 (3 -> 64, s2): 256 -> 128, batch-halved for T1 memory ---
    conv1x1_k<3, 2, false><<<dim3(32 * 64 * 2), blk, 0, stream>>>(
        x, e0wd, e0bd, S0, 64, 256, 256, 128, 128);
    for (int h = 0; h < 2; ++h) {
        const float* xh = x + (size_t)h * 16 * 3 * 65536;
        float* s0h = S0 + (size_t)h * 16 * 64 * 16384;
        conv3s2_k<3, 3, true><<<dim3(16 * 8 * 4 * 2), blk, 0, stream>>>(
            xh, P_e0w1, e0b1, T1h, 64, 256, 256);
        conv3s1_k<64, 8, true, true><<<dim3(16 * 8 * 4 * 2), blk, 0, stream>>>(
            T1h, P_e0w2, e0b2, s0h, s0h, 64, 128, 128);
    }

    // --- enc1 (64 -> 128, s2): 128 -> 64, full batch ---
    conv1x1_k<64, 2, false><<<dim3(32 * 16 * 4), blk, 0, stream>>>(
        S0, e1wd, e1bd, S1, 128, 128, 128, 64, 64);
    conv3s2_k<64, 4, true><<<dim3(32 * 4 * 2 * 4), blk, 0, stream>>>(
        S0, P_e1w1, e1b1, T3, 128, 128, 128);
    conv3s1_k<128, 8, true, true><<<dim3(32 * 4 * 2 * 4), blk, 0, stream>>>(
        T3, P_e1w2, e1b2, S1, S1, 128, 64, 64);
    rp(d1w, P_d1w, 64, 64, 128, 0, 1);          // T3 now dead

    // --- enc2 (128 -> 64, s1) ---
    conv1x1_k<128, 1, false><<<dim3(32 * 16 * 2), blk, 0, stream>>>(
        S1, e2wd, e2bd, S2, 64, 64, 64, 64, 64);
    conv3s1_k<128, 8, true, false><<<dim3(32 * 4 * 2 * 2), blk, 0, stream>>>(
        S1, P_e2w1, e2b1, T5, nullptr, 64, 64, 64);
    conv3s1_k<64, 8, true, true><<<dim3(32 * 4 * 2 * 2), blk, 0, stream>>>(
        T5, P_e2w2, e2b2, S2, S2, 64, 64, 64);

    // --- quantize ---
    quantize_k<<<dim3(512), blk, 0, stream>>>(S2, cb, Q);

    // --- dec0: ConvT s1 (64 -> 128) as flipped conv, ReLU ---
    conv3s1_k<64, 8, true, false><<<dim3(32 * 4 * 2 * 4), blk, 0, stream>>>(
        Q, P_d0w, d0b, D0, nullptr, 128, 64, 64);

    // --- dec1: ConvT s2 (128 -> 64), ReLU: 64 -> 128 ---
    deconv2_k<128, 4, 16, true><<<dim3(32 * 4 * 2 * 4), blk, 0, stream>>>(
        D0, P_d1w, d1b, D1, 64, 64, 64, 64);

    // --- dec2: ConvT s2 (64 -> 3): 128 -> 256 ---
    rp(d2w, P_d2w, 4, 3, 64, 0, 1);             // D0 now dead
    deconv2_k<64, 8, 4, false><<<dim3(32 * 8 * 4 * 1), blk, 0, stream>>>(
        D1, P_d2w, d2b, out, 3, 4, 128, 128);
}